// Round 1
// baseline (1434.245 us; speedup 1.0000x reference)
//
#include <hip/hip_runtime.h>
#include <math.h>

#define NG 64

__device__ __forceinline__ float leaky(float x){ return x > 0.f ? x : 0.2f*x; }

__device__ __forceinline__ int lowbound(const int* __restrict__ a, int n, int v){
  int lo = 0, hi = n;
  while (lo < hi){ int mid = (lo + hi) >> 1; if (a[mid] < v) lo = mid + 1; else hi = mid; }
  return lo;
}

__global__ void k_zero_i32(int* __restrict__ p, int n){
  int i = blockIdx.x * 256 + threadIdx.x; if (i < n) p[i] = 0;
}
__global__ void k_zero_f32(float* __restrict__ p, int n){
  int i = blockIdx.x * 256 + threadIdx.x; if (i < n) p[i] = 0.f;
}

// count incoming edges per dst (incl. self loops)
__global__ void k_count(const int* __restrict__ ei, int E, int N, int* __restrict__ cnt){
  int e = blockIdx.x * 256 + threadIdx.x;
  if (e >= E + N) return;
  int d = (e < E) ? ei[E + e] : (e - E);
  atomicAdd(&cnt[d], 1);
}

// single-block chunked exclusive scan -> row_start[0..N], cur = row_start copy
__global__ __launch_bounds__(1024) void k_scan(const int* __restrict__ cnt, int N,
                                               int* __restrict__ row_start, int* __restrict__ cur){
  __shared__ int sp[1024];
  int t = threadIdx.x;
  int C = (N + 1023) >> 10;
  int lo = t * C, hi = min(lo + C, N);
  int s = 0;
  for (int i = lo; i < hi; ++i) s += cnt[i];
  sp[t] = s;
  __syncthreads();
  for (int off = 1; off < 1024; off <<= 1){
    int v = (t >= off) ? sp[t - off] : 0;
    __syncthreads();
    sp[t] += v;
    __syncthreads();
  }
  int run = (t == 0) ? 0 : sp[t - 1];
  for (int i = lo; i < hi; ++i){ row_start[i] = run; cur[i] = run; run += cnt[i]; }
  if (t == 1023) row_start[N] = sp[1023];
}

__global__ void k_fill(const int* __restrict__ ei, int E, int N,
                       int* __restrict__ cur, int* __restrict__ col){
  int e = blockIdx.x * 256 + threadIdx.x;
  if (e >= E + N) return;
  int s, d;
  if (e < E){ s = ei[e]; d = ei[E + e]; } else { s = e - E; d = s; }
  int pos = atomicAdd(&cur[d], 1);
  col[pos] = s;
}

// ---------------- GEMM: H[N,DOUT] = X[N,DIN] @ W[DIN,DOUT] ----------------
template<int DIN, int DOUT, int BN>
__global__ __launch_bounds__(256) void k_gemm(const float* __restrict__ X,
                                              const float* __restrict__ W,
                                              float* __restrict__ H, int N){
  constexpr int BM = 128, BK = 32, TM = 8;
  constexpr int TN = BN / 16;
  static_assert(DIN % BK == 0 && DOUT % BN == 0 && (TN == 2 || TN == 4), "shape");
  __shared__ float xs[BK][BM];
  __shared__ float wsm[BK][BN];
  int m0 = blockIdx.x * BM;
  int n0 = blockIdx.y * BN;
  int tid = threadIdx.x;
  int tc = tid & 15, tr = tid >> 4;
  float acc[TM][TN];
#pragma unroll
  for (int i = 0; i < TM; ++i)
#pragma unroll
    for (int j = 0; j < TN; ++j) acc[i][j] = 0.f;

  for (int kt = 0; kt < DIN; kt += BK){
    __syncthreads();
    // X tile (transposed into LDS): 128 rows x 32 k
    for (int t = tid; t < BM * BK / 4; t += 256){
      int m = t >> 3, kq = t & 7;
      float4 v = make_float4(0.f, 0.f, 0.f, 0.f);
      int row = m0 + m;
      if (row < N) v = *(const float4*)(X + (size_t)row * DIN + kt + kq * 4);
      xs[kq * 4 + 0][m] = v.x; xs[kq * 4 + 1][m] = v.y;
      xs[kq * 4 + 2][m] = v.z; xs[kq * 4 + 3][m] = v.w;
    }
    // W tile
    for (int t = tid; t < BK * BN / 4; t += 256){
      int k = t / (BN / 4), nq = t % (BN / 4);
      float4 v = *(const float4*)(W + (size_t)(kt + k) * DOUT + n0 + nq * 4);
      *(float4*)(&wsm[k][nq * 4]) = v;
    }
    __syncthreads();
#pragma unroll
    for (int k = 0; k < BK; ++k){
      float a[TM], b[TN];
      *(float4*)&a[0] = *(const float4*)&xs[k][tr * TM];
      *(float4*)&a[4] = *(const float4*)&xs[k][tr * TM + 4];
      if constexpr (TN == 4) *(float4*)&b[0] = *(const float4*)&wsm[k][tc * 4];
      else                   *(float2*)&b[0] = *(const float2*)&wsm[k][tc * 2];
#pragma unroll
      for (int i = 0; i < TM; ++i)
#pragma unroll
        for (int j = 0; j < TN; ++j) acc[i][j] = fmaf(a[i], b[j], acc[i][j]);
    }
  }
#pragma unroll
  for (int i = 0; i < TM; ++i){
    int row = m0 + tr * TM + i;
    if (row < N){
      if constexpr (TN == 4) *(float4*)&H[(size_t)row * DOUT + n0 + tc * 4] = *(float4*)acc[i];
      else                   *(float2*)&H[(size_t)row * DOUT + n0 + tc * 2] = *(float2*)acc[i];
    }
  }
}

// ---------------- attention projections: al_s/al_d = h . a ----------------
template<int DOUT>
__global__ __launch_bounds__(256) void k_alpha(const float* __restrict__ H,
                                               const float* __restrict__ a_src,
                                               const float* __restrict__ a_dst,
                                               float* __restrict__ als, float* __restrict__ ald, int N){
  int wave = threadIdx.x >> 6, lane = threadIdx.x & 63;
  int i = blockIdx.x * 4 + wave;
  if (i >= N) return;
  float ss = 0.f, sd = 0.f;
#pragma unroll
  for (int cb = 0; cb < (DOUT + 63) / 64; ++cb){
    int ch = cb * 64 + lane;
    if (DOUT % 64 == 0 || ch < DOUT){
      float h = H[(size_t)i * DOUT + ch];
      ss = fmaf(h, a_src[ch], ss);
      sd = fmaf(h, a_dst[ch], sd);
    }
  }
  for (int o = 32; o > 0; o >>= 1){ ss += __shfl_xor(ss, o); sd += __shfl_xor(sd, o); }
  if (lane == 0){ als[i] = ss; ald[i] = sd; }
}

// ---------------- per-node segment softmax + weighted aggregation ----------------
template<int DOUT>
__global__ __launch_bounds__(256) void k_agg(const float* __restrict__ H,
                                             const int* __restrict__ row_start,
                                             const int* __restrict__ col,
                                             const float* __restrict__ als,
                                             const float* __restrict__ ald,
                                             const float* __restrict__ bias,
                                             float* __restrict__ OUTB, int N){
  int wave = threadIdx.x >> 6, lane = threadIdx.x & 63;
  int i = blockIdx.x * 4 + wave;
  if (i >= N) return;
  int beg = row_start[i], end = row_start[i + 1];
  float ad = ald[i];
  // pass 1: max over incident edges
  float m = -1e30f;
  for (int j = beg + lane; j < end; j += 64){
    float e = leaky(als[col[j]] + ad);
    m = fmaxf(m, e);
  }
  for (int o = 32; o > 0; o >>= 1) m = fmaxf(m, __shfl_xor(m, o));
  // pass 2: sum of exp
  float s = 0.f;
  for (int j = beg + lane; j < end; j += 64){
    float e = leaky(als[col[j]] + ad);
    s += __expf(e - m);
  }
  for (int o = 32; o > 0; o >>= 1) s += __shfl_xor(s, o);
  float inv = 1.0f / s;

  constexpr int CB = (DOUT >= 64) ? DOUT / 64 : 1;
  float acc[CB];
#pragma unroll
  for (int cb = 0; cb < CB; ++cb) acc[cb] = 0.f;

  if constexpr (DOUT >= 64){
    for (int j = beg; j < end; ++j){
      int sn = col[j];
      float e = leaky(als[sn] + ad);
      float w = __expf(e - m) * inv;
#pragma unroll
      for (int cb = 0; cb < CB; ++cb)
        acc[cb] = fmaf(w, H[(size_t)sn * DOUT + cb * 64 + lane], acc[cb]);
    }
#pragma unroll
    for (int cb = 0; cb < CB; ++cb){
      int ch = cb * 64 + lane;
      float o = acc[cb] + bias[ch];
      o = o > 0.f ? o : __expf(o) - 1.f;
      OUTB[(size_t)i * DOUT + ch] = o;
    }
  } else { // DOUT == 32: two edges per iteration (lane halves)
    int half = lane >> 5, ch = lane & 31;
    for (int j = beg; j < end; j += 2){
      int jj = j + half;
      if (jj < end){
        int sn = col[jj];
        float e = leaky(als[sn] + ad);
        float w = __expf(e - m) * inv;
        acc[0] = fmaf(w, H[(size_t)sn * DOUT + ch], acc[0]);
      }
    }
    acc[0] += __shfl_xor(acc[0], 32);
    if (lane < 32){
      float o = acc[0] + bias[ch];
      o = o > 0.f ? o : __expf(o) - 1.f;
      OUTB[(size_t)i * DOUT + ch] = o;
    }
  }
}

// ---------------- pooling: per-chunk run-length accumulate ----------------
__global__ __launch_bounds__(256) void k_pool(const float* __restrict__ X4,
                                              const int* __restrict__ batch, int N,
                                              float* __restrict__ g){
  int ch = threadIdx.x; // 256 channels
  int nPer = (N + gridDim.x - 1) / gridDim.x;
  int n0 = blockIdx.x * nPer, n1 = min(n0 + nPer, N);
  if (n0 >= n1) return;
  float acc = 0.f;
  int cg = batch[n0];
  for (int n = n0; n < n1; ++n){
    int gb = batch[n];
    if (gb != cg){ atomicAdd(&g[cg * 256 + ch], acc); acc = 0.f; cg = gb; }
    acc += X4[(size_t)n * 256 + ch];
  }
  atomicAdd(&g[cg * 256 + ch], acc);
}

// ---------------- fused mean + MLP head ----------------
__global__ __launch_bounds__(128) void k_mlp(const float* __restrict__ g,
                                             const int* __restrict__ batch, int N,
                                             const float* __restrict__ l1w, const float* __restrict__ l1b,
                                             const float* __restrict__ l2w, const float* __restrict__ l2b,
                                             float* __restrict__ out){
  __shared__ float gb[256];
  __shared__ float hb[128];
  int gi = blockIdx.x, t = threadIdx.x;
  int lo = lowbound(batch, N, gi);
  int hi = lowbound(batch, N, gi + 1);
  float invc = 1.0f / fmaxf((float)(hi - lo), 1.0f);
  gb[t]       = g[gi * 256 + t] * invc;
  gb[t + 128] = g[gi * 256 + t + 128] * invc;
  __syncthreads();
  float s = l1b[t];
  for (int k = 0; k < 256; ++k) s = fmaf(gb[k], l1w[k * 128 + t], s);
  s = s > 0.f ? s : __expf(s) - 1.f;
  hb[t] = s;
  __syncthreads();
  if (t < 10){
    float o = l2b[t];
    for (int k = 0; k < 128; ++k) o = fmaf(hb[k], l2w[k * 10 + t], o);
    out[gi * 10 + t] = o;
  }
}

// ---------------- host side ----------------
template<int DIN, int DOUT>
static void run_layer(const float* xin, const float* W, const float* asrc, const float* adst,
                      const float* bias, float* H, float* OUTB,
                      const int* rs, const int* col, float* als, float* ald,
                      int N, hipStream_t stream){
  constexpr int BN = (DOUT < 64) ? DOUT : 64;
  dim3 grid((N + 127) / 128, DOUT / BN);
  k_gemm<DIN, DOUT, BN><<<grid, 256, 0, stream>>>(xin, W, H, N);
  int nb = (N + 3) / 4;
  k_alpha<DOUT><<<nb, 256, 0, stream>>>(H, asrc, adst, als, ald, N);
  k_agg<DOUT><<<nb, 256, 0, stream>>>(H, rs, col, als, ald, bias, OUTB, N);
}

extern "C" void kernel_launch(void* const* d_in, const int* in_sizes, int n_in,
                              void* d_out, int out_size, void* d_ws, size_t ws_size,
                              hipStream_t stream){
  const float* x     = (const float*)d_in[0];
  const int*   ei    = (const int*)  d_in[1];
  const int*   batch = (const int*)  d_in[2];
  const float* W1  = (const float*)d_in[3];
  const float* as1 = (const float*)d_in[4];
  const float* ad1 = (const float*)d_in[5];
  const float* b1  = (const float*)d_in[6];
  const float* W2  = (const float*)d_in[7];
  const float* as2 = (const float*)d_in[8];
  const float* ad2 = (const float*)d_in[9];
  const float* b2  = (const float*)d_in[10];
  const float* W3  = (const float*)d_in[11];
  const float* as3 = (const float*)d_in[12];
  const float* ad3 = (const float*)d_in[13];
  const float* b3  = (const float*)d_in[14];
  const float* W4  = (const float*)d_in[15];
  const float* as4 = (const float*)d_in[16];
  const float* ad4 = (const float*)d_in[17];
  const float* b4  = (const float*)d_in[18];
  const float* l1w = (const float*)d_in[19];
  const float* l1b = (const float*)d_in[20];
  const float* l2w = (const float*)d_in[21];
  const float* l2b = (const float*)d_in[22];

  int N  = in_sizes[2];
  int E  = in_sizes[1] / 2;
  int EN = E + N;

  char* p = (char*)d_ws;
  auto alloc = [&](size_t bytes){ void* r = (void*)p; p += (bytes + 255) & ~(size_t)255; return r; };
  float* H    = (float*)alloc((size_t)N * 256 * 4);
  float* OUTB = (float*)alloc((size_t)N * 256 * 4);
  int*   cnt  = (int*)  alloc((size_t)N * 4);
  int*   cur  = (int*)  alloc((size_t)N * 4);
  int*   rs   = (int*)  alloc((size_t)(N + 1) * 4);
  int*   col  = (int*)  alloc((size_t)EN * 4);
  float* als  = (float*)alloc((size_t)N * 4);
  float* ald  = (float*)alloc((size_t)N * 4);
  float* g    = (float*)alloc((size_t)NG * 256 * 4);

  // CSR build (by destination, self-loops appended)
  k_zero_i32<<<(N + 255) / 256, 256, 0, stream>>>(cnt, N);
  k_count<<<(EN + 255) / 256, 256, 0, stream>>>(ei, E, N, cnt);
  k_scan<<<1, 1024, 0, stream>>>(cnt, N, rs, cur);
  k_fill<<<(EN + 255) / 256, 256, 0, stream>>>(ei, E, N, cur, col);

  // 4 GAT layers (H = h buffer, OUTB = layer output, ping-pong in place)
  run_layer<128,  32>(x,    W1, as1, ad1, b1, H, OUTB, rs, col, als, ald, N, stream);
  run_layer< 32,  64>(OUTB, W2, as2, ad2, b2, H, OUTB, rs, col, als, ald, N, stream);
  run_layer< 64, 128>(OUTB, W3, as3, ad3, b3, H, OUTB, rs, col, als, ald, N, stream);
  run_layer<128, 256>(OUTB, W4, as4, ad4, b4, H, OUTB, rs, col, als, ald, N, stream);

  // global mean pool + MLP head
  k_zero_f32<<<(NG * 256 + 255) / 256, 256, 0, stream>>>(g, NG * 256);
  k_pool<<<1024, 256, 0, stream>>>(OUTB, batch, N, g);
  k_mlp<<<NG, 128, 0, stream>>>(g, batch, N, l1w, l1b, l2w, l2b, (float*)d_out);
}

// Round 2
// 1285.810 us; speedup vs baseline: 1.1154x; 1.1154x over previous
//
#include <hip/hip_runtime.h>
#include <math.h>

#define NG 64

__device__ __forceinline__ float leaky(float x){ return x > 0.f ? x : 0.2f*x; }

__device__ __forceinline__ int lowbound(const int* __restrict__ a, int n, int v){
  int lo = 0, hi = n;
  while (lo < hi){ int mid = (lo + hi) >> 1; if (a[mid] < v) lo = mid + 1; else hi = mid; }
  return lo;
}

__global__ void k_zero_i32(int* __restrict__ p, int n){
  int i = blockIdx.x * 256 + threadIdx.x; if (i < n) p[i] = 0;
}
__global__ void k_zero_f32(float* __restrict__ p, int n){
  int i = blockIdx.x * 256 + threadIdx.x; if (i < n) p[i] = 0.f;
}

// count incoming edges per dst (incl. self loops)
__global__ void k_count(const int* __restrict__ ei, int E, int N, int* __restrict__ cnt){
  int e = blockIdx.x * 256 + threadIdx.x;
  if (e >= E + N) return;
  int d = (e < E) ? ei[E + e] : (e - E);
  atomicAdd(&cnt[d], 1);
}

// single-block chunked exclusive scan -> row_start[0..N], cur = row_start copy
__global__ __launch_bounds__(1024) void k_scan(const int* __restrict__ cnt, int N,
                                               int* __restrict__ row_start, int* __restrict__ cur){
  __shared__ int sp[1024];
  int t = threadIdx.x;
  int C = (N + 1023) >> 10;
  int lo = t * C, hi = min(lo + C, N);
  int s = 0;
  for (int i = lo; i < hi; ++i) s += cnt[i];
  sp[t] = s;
  __syncthreads();
  for (int off = 1; off < 1024; off <<= 1){
    int v = (t >= off) ? sp[t - off] : 0;
    __syncthreads();
    sp[t] += v;
    __syncthreads();
  }
  int run = (t == 0) ? 0 : sp[t - 1];
  for (int i = lo; i < hi; ++i){ row_start[i] = run; cur[i] = run; run += cnt[i]; }
  if (t == 1023) row_start[N] = sp[1023];
}

__global__ void k_fill(const int* __restrict__ ei, int E, int N,
                       int* __restrict__ cur, int* __restrict__ col){
  int e = blockIdx.x * 256 + threadIdx.x;
  if (e >= E + N) return;
  int s, d;
  if (e < E){ s = ei[e]; d = ei[E + e]; } else { s = e - E; d = s; }
  int pos = atomicAdd(&cur[d], 1);
  col[pos] = s;
}

// ---------------- GEMM: H[N,DOUT] = X[N,DIN] @ W[DIN,DOUT] ----------------
template<int DIN, int DOUT, int BN>
__global__ __launch_bounds__(256) void k_gemm(const float* __restrict__ X,
                                              const float* __restrict__ W,
                                              float* __restrict__ H, int N){
  constexpr int BM = 128, BK = 32, TM = 8;
  constexpr int TN = BN / 16;
  static_assert(DIN % BK == 0 && DOUT % BN == 0 && (TN == 2 || TN == 4), "shape");
  __shared__ float xs[BK][BM];
  __shared__ float wsm[BK][BN];
  int m0 = blockIdx.x * BM;
  int n0 = blockIdx.y * BN;
  int tid = threadIdx.x;
  int tc = tid & 15, tr = tid >> 4;
  float acc[TM][TN];
#pragma unroll
  for (int i = 0; i < TM; ++i)
#pragma unroll
    for (int j = 0; j < TN; ++j) acc[i][j] = 0.f;

  for (int kt = 0; kt < DIN; kt += BK){
    __syncthreads();
    for (int t = tid; t < BM * BK / 4; t += 256){
      int m = t >> 3, kq = t & 7;
      float4 v = make_float4(0.f, 0.f, 0.f, 0.f);
      int row = m0 + m;
      if (row < N) v = *(const float4*)(X + (size_t)row * DIN + kt + kq * 4);
      xs[kq * 4 + 0][m] = v.x; xs[kq * 4 + 1][m] = v.y;
      xs[kq * 4 + 2][m] = v.z; xs[kq * 4 + 3][m] = v.w;
    }
    for (int t = tid; t < BK * BN / 4; t += 256){
      int k = t / (BN / 4), nq = t % (BN / 4);
      float4 v = *(const float4*)(W + (size_t)(kt + k) * DOUT + n0 + nq * 4);
      *(float4*)(&wsm[k][nq * 4]) = v;
    }
    __syncthreads();
#pragma unroll
    for (int k = 0; k < BK; ++k){
      float a[TM], b[TN];
      *(float4*)&a[0] = *(const float4*)&xs[k][tr * TM];
      *(float4*)&a[4] = *(const float4*)&xs[k][tr * TM + 4];
      if constexpr (TN == 4) *(float4*)&b[0] = *(const float4*)&wsm[k][tc * 4];
      else                   *(float2*)&b[0] = *(const float2*)&wsm[k][tc * 2];
#pragma unroll
      for (int i = 0; i < TM; ++i)
#pragma unroll
        for (int j = 0; j < TN; ++j) acc[i][j] = fmaf(a[i], b[j], acc[i][j]);
    }
  }
#pragma unroll
  for (int i = 0; i < TM; ++i){
    int row = m0 + tr * TM + i;
    if (row < N){
      if constexpr (TN == 4) *(float4*)&H[(size_t)row * DOUT + n0 + tc * 4] = *(float4*)acc[i];
      else                   *(float2*)&H[(size_t)row * DOUT + n0 + tc * 2] = *(float2*)acc[i];
    }
  }
}

// ---------------- attention projections: al_s/al_d = h . a ----------------
template<int DOUT>
__global__ __launch_bounds__(256) void k_alpha(const float* __restrict__ H,
                                               const float* __restrict__ a_src,
                                               const float* __restrict__ a_dst,
                                               float* __restrict__ als, float* __restrict__ ald, int N){
  int wave = threadIdx.x >> 6, lane = threadIdx.x & 63;
  int i = blockIdx.x * 4 + wave;
  if (i >= N) return;
  float ss = 0.f, sd = 0.f;
#pragma unroll
  for (int cb = 0; cb < (DOUT + 63) / 64; ++cb){
    int ch = cb * 64 + lane;
    if (DOUT % 64 == 0 || ch < DOUT){
      float h = H[(size_t)i * DOUT + ch];
      ss = fmaf(h, a_src[ch], ss);
      sd = fmaf(h, a_dst[ch], sd);
    }
  }
  for (int o = 32; o > 0; o >>= 1){ ss += __shfl_xor(ss, o); sd += __shfl_xor(sd, o); }
  if (lane == 0){ als[i] = ss; ald[i] = sd; }
}

// ---------------- per-edge softmax numerator + per-node denominator ----------------
__global__ __launch_bounds__(256) void k_attn(const int* __restrict__ row_start,
                                              const int* __restrict__ col,
                                              const float* __restrict__ als,
                                              const float* __restrict__ ald,
                                              float* __restrict__ alpha,
                                              float* __restrict__ denom, int N){
  int wave = threadIdx.x >> 6, lane = threadIdx.x & 63;
  int i = blockIdx.x * 4 + wave;
  if (i >= N) return;
  int beg = row_start[i], end = row_start[i + 1];
  float ad = ald[i];
  // pass 1: max
  float m = -1e30f;
  for (int j = beg + lane; j < end; j += 64)
    m = fmaxf(m, leaky(als[col[j]] + ad));
  for (int o = 32; o > 0; o >>= 1) m = fmaxf(m, __shfl_xor(m, o));
  // pass 2: exp, write numerator, reduce denominator
  float s = 0.f;
  for (int j = beg + lane; j < end; j += 64){
    float x = __expf(leaky(als[col[j]] + ad) - m);
    alpha[j] = x;
    s += x;
  }
  for (int o = 32; o > 0; o >>= 1) s += __shfl_xor(s, o);
  if (lane == 0) denom[i] = s;
}

// ---------------- weighted gather: out[i][ch] = (1/denom) * sum_j alpha[j]*H[col[j]][ch] ----------------
template<int DOUT>
__global__ __launch_bounds__(256) void k_agg2(const float* __restrict__ H,
                                              const int* __restrict__ row_start,
                                              const int* __restrict__ col,
                                              const float* __restrict__ alpha,
                                              const float* __restrict__ denom,
                                              const float* __restrict__ bias,
                                              float* __restrict__ OUTB, int N){
  int wave = threadIdx.x >> 6, lane = threadIdx.x & 63;
  int i = blockIdx.x * 4 + wave;
  if (i >= N) return;
  int beg = row_start[i], end = row_start[i + 1];
  int deg = end - beg;
  float inv = 1.0f / denom[i];

  if constexpr (DOUT >= 64){
    int ch = blockIdx.y * 64 + lane;
    const float* __restrict__ Hc = H + ch;
    float a0 = 0.f, a1 = 0.f, a2 = 0.f, a3 = 0.f;
    for (int base = 0; base < deg; base += 64){
      int cnt = min(64, deg - base);
      int   sn_v = (base + lane < deg) ? col[beg + base + lane]   : 0;
      float w_v  = (base + lane < deg) ? alpha[beg + base + lane] : 0.f;
      int k = 0;
      for (; k + 3 < cnt; k += 4){
        int   s0 = __shfl(sn_v, k),     s1 = __shfl(sn_v, k + 1);
        int   s2 = __shfl(sn_v, k + 2), s3 = __shfl(sn_v, k + 3);
        float w0 = __shfl(w_v, k),      w1 = __shfl(w_v, k + 1);
        float w2 = __shfl(w_v, k + 2),  w3 = __shfl(w_v, k + 3);
        a0 = fmaf(w0, Hc[(size_t)s0 * DOUT], a0);
        a1 = fmaf(w1, Hc[(size_t)s1 * DOUT], a1);
        a2 = fmaf(w2, Hc[(size_t)s2 * DOUT], a2);
        a3 = fmaf(w3, Hc[(size_t)s3 * DOUT], a3);
      }
      for (; k < cnt; ++k){
        int s0 = __shfl(sn_v, k); float w0 = __shfl(w_v, k);
        a0 = fmaf(w0, Hc[(size_t)s0 * DOUT], a0);
      }
    }
    float o = ((a0 + a1) + (a2 + a3)) * inv + bias[ch];
    o = o > 0.f ? o : __expf(o) - 1.f;
    OUTB[(size_t)i * DOUT + ch] = o;
  } else { // DOUT == 32: lanes = 2 edge-slots x 32 channels
    int half = lane >> 5, ch = lane & 31;
    const float* __restrict__ Hc = H + ch;
    float a0 = 0.f, a1 = 0.f, a2 = 0.f, a3 = 0.f;
    for (int base = 0; base < deg; base += 64){
      int cnt = min(64, deg - base);
      int   sn_v = (base + lane < deg) ? col[beg + base + lane]   : 0;
      float w_v  = (base + lane < deg) ? alpha[beg + base + lane] : 0.f;
      int k = 0;
      for (; k + 7 < cnt; k += 8){
        int   e0 = k + half, e1 = k + 2 + half, e2 = k + 4 + half, e3 = k + 6 + half;
        int   s0 = __shfl(sn_v, e0), s1 = __shfl(sn_v, e1);
        int   s2 = __shfl(sn_v, e2), s3 = __shfl(sn_v, e3);
        float w0 = __shfl(w_v, e0),  w1 = __shfl(w_v, e1);
        float w2 = __shfl(w_v, e2),  w3 = __shfl(w_v, e3);
        a0 = fmaf(w0, Hc[(size_t)s0 * DOUT], a0);
        a1 = fmaf(w1, Hc[(size_t)s1 * DOUT], a1);
        a2 = fmaf(w2, Hc[(size_t)s2 * DOUT], a2);
        a3 = fmaf(w3, Hc[(size_t)s3 * DOUT], a3);
      }
      for (; k < cnt; k += 2){
        int e0 = k + half;
        if (e0 < cnt){
          int s0 = __shfl(sn_v, e0); float w0 = __shfl(w_v, e0);
          a0 = fmaf(w0, Hc[(size_t)s0 * DOUT], a0);
        }
      }
    }
    float acc = (a0 + a1) + (a2 + a3);
    acc += __shfl_xor(acc, 32);
    if (lane < 32){
      float o = acc * inv + bias[ch];
      o = o > 0.f ? o : __expf(o) - 1.f;
      OUTB[(size_t)i * DOUT + ch] = o;
    }
  }
}

// ---------------- pooling: per-chunk run-length accumulate ----------------
__global__ __launch_bounds__(256) void k_pool(const float* __restrict__ X4,
                                              const int* __restrict__ batch, int N,
                                              float* __restrict__ g){
  int ch = threadIdx.x; // 256 channels
  int nPer = (N + gridDim.x - 1) / gridDim.x;
  int n0 = blockIdx.x * nPer, n1 = min(n0 + nPer, N);
  if (n0 >= n1) return;
  float acc = 0.f;
  int cg = batch[n0];
  for (int n = n0; n < n1; ++n){
    int gb = batch[n];
    if (gb != cg){ atomicAdd(&g[cg * 256 + ch], acc); acc = 0.f; cg = gb; }
    acc += X4[(size_t)n * 256 + ch];
  }
  atomicAdd(&g[cg * 256 + ch], acc);
}

// ---------------- fused mean + MLP head ----------------
__global__ __launch_bounds__(128) void k_mlp(const float* __restrict__ g,
                                             const int* __restrict__ batch, int N,
                                             const float* __restrict__ l1w, const float* __restrict__ l1b,
                                             const float* __restrict__ l2w, const float* __restrict__ l2b,
                                             float* __restrict__ out){
  __shared__ float gb[256];
  __shared__ float hb[128];
  int gi = blockIdx.x, t = threadIdx.x;
  int lo = lowbound(batch, N, gi);
  int hi = lowbound(batch, N, gi + 1);
  float invc = 1.0f / fmaxf((float)(hi - lo), 1.0f);
  gb[t]       = g[gi * 256 + t] * invc;
  gb[t + 128] = g[gi * 256 + t + 128] * invc;
  __syncthreads();
  float s = l1b[t];
  for (int k = 0; k < 256; ++k) s = fmaf(gb[k], l1w[k * 128 + t], s);
  s = s > 0.f ? s : __expf(s) - 1.f;
  hb[t] = s;
  __syncthreads();
  if (t < 10){
    float o = l2b[t];
    for (int k = 0; k < 128; ++k) o = fmaf(hb[k], l2w[k * 10 + t], o);
    out[gi * 10 + t] = o;
  }
}

// ---------------- host side ----------------
template<int DIN, int DOUT>
static void run_layer(const float* xin, const float* W, const float* asrc, const float* adst,
                      const float* bias, float* H, float* OUTB,
                      const int* rs, const int* col, float* als, float* ald,
                      float* alpha, float* denom,
                      int N, hipStream_t stream){
  constexpr int BN = (DOUT < 64) ? DOUT : 64;
  dim3 grid((N + 127) / 128, DOUT / BN);
  k_gemm<DIN, DOUT, BN><<<grid, 256, 0, stream>>>(xin, W, H, N);
  int nb = (N + 3) / 4;
  k_alpha<DOUT><<<nb, 256, 0, stream>>>(H, asrc, adst, als, ald, N);
  k_attn<<<nb, 256, 0, stream>>>(rs, col, als, ald, alpha, denom, N);
  constexpr int CB = (DOUT >= 64) ? DOUT / 64 : 1;
  dim3 ga(nb, CB);
  k_agg2<DOUT><<<ga, 256, 0, stream>>>(H, rs, col, alpha, denom, bias, OUTB, N);
}

extern "C" void kernel_launch(void* const* d_in, const int* in_sizes, int n_in,
                              void* d_out, int out_size, void* d_ws, size_t ws_size,
                              hipStream_t stream){
  const float* x     = (const float*)d_in[0];
  const int*   ei    = (const int*)  d_in[1];
  const int*   batch = (const int*)  d_in[2];
  const float* W1  = (const float*)d_in[3];
  const float* as1 = (const float*)d_in[4];
  const float* ad1 = (const float*)d_in[5];
  const float* b1  = (const float*)d_in[6];
  const float* W2  = (const float*)d_in[7];
  const float* as2 = (const float*)d_in[8];
  const float* ad2 = (const float*)d_in[9];
  const float* b2  = (const float*)d_in[10];
  const float* W3  = (const float*)d_in[11];
  const float* as3 = (const float*)d_in[12];
  const float* ad3 = (const float*)d_in[13];
  const float* b3  = (const float*)d_in[14];
  const float* W4  = (const float*)d_in[15];
  const float* as4 = (const float*)d_in[16];
  const float* ad4 = (const float*)d_in[17];
  const float* b4  = (const float*)d_in[18];
  const float* l1w = (const float*)d_in[19];
  const float* l1b = (const float*)d_in[20];
  const float* l2w = (const float*)d_in[21];
  const float* l2b = (const float*)d_in[22];

  int N  = in_sizes[2];
  int E  = in_sizes[1] / 2;
  int EN = E + N;

  char* p = (char*)d_ws;
  auto alloc = [&](size_t bytes){ void* r = (void*)p; p += (bytes + 255) & ~(size_t)255; return r; };
  float* H     = (float*)alloc((size_t)N * 256 * 4);
  float* OUTB  = (float*)alloc((size_t)N * 256 * 4);
  int*   cnt   = (int*)  alloc((size_t)N * 4);
  int*   cur   = (int*)  alloc((size_t)N * 4);
  int*   rs    = (int*)  alloc((size_t)(N + 1) * 4);
  int*   col   = (int*)  alloc((size_t)EN * 4);
  float* als   = (float*)alloc((size_t)N * 4);
  float* ald   = (float*)alloc((size_t)N * 4);
  float* alpha = (float*)alloc((size_t)EN * 4);
  float* denom = (float*)alloc((size_t)N * 4);
  float* g     = (float*)alloc((size_t)NG * 256 * 4);

  // CSR build (by destination, self-loops appended)
  k_zero_i32<<<(N + 255) / 256, 256, 0, stream>>>(cnt, N);
  k_count<<<(EN + 255) / 256, 256, 0, stream>>>(ei, E, N, cnt);
  k_scan<<<1, 1024, 0, stream>>>(cnt, N, rs, cur);
  k_fill<<<(EN + 255) / 256, 256, 0, stream>>>(ei, E, N, cur, col);

  // 4 GAT layers
  run_layer<128,  32>(x,    W1, as1, ad1, b1, H, OUTB, rs, col, als, ald, alpha, denom, N, stream);
  run_layer< 32,  64>(OUTB, W2, as2, ad2, b2, H, OUTB, rs, col, als, ald, alpha, denom, N, stream);
  run_layer< 64, 128>(OUTB, W3, as3, ad3, b3, H, OUTB, rs, col, als, ald, alpha, denom, N, stream);
  run_layer<128, 256>(OUTB, W4, as4, ad4, b4, H, OUTB, rs, col, als, ald, alpha, denom, N, stream);

  // global mean pool + MLP head
  k_zero_f32<<<(NG * 256 + 255) / 256, 256, 0, stream>>>(g, NG * 256);
  k_pool<<<1024, 256, 0, stream>>>(OUTB, batch, N, g);
  k_mlp<<<NG, 128, 0, stream>>>(g, batch, N, l1w, l1b, l2w, l2b, (float*)d_out);
}

// Round 3
// 1026.120 us; speedup vs baseline: 1.3977x; 1.2531x over previous
//
#include <hip/hip_runtime.h>
#include <math.h>

#define NG 64

typedef unsigned int uint;
typedef unsigned short ushort;

__device__ __forceinline__ float leaky(float x){ return x > 0.f ? x : 0.2f*x; }

__device__ __forceinline__ ushort f2bf(float f){
  uint u = __float_as_uint(f);
  uint r = (u + 0x7FFFu + ((u >> 16) & 1u)) >> 16;
  return (ushort)r;
}

__device__ __forceinline__ int lowbound(const int* __restrict__ a, int n, int v){
  int lo = 0, hi = n;
  while (lo < hi){ int mid = (lo + hi) >> 1; if (a[mid] < v) lo = mid + 1; else hi = mid; }
  return lo;
}

__global__ void k_zero_i32(int* __restrict__ p, int n){
  int i = blockIdx.x * 256 + threadIdx.x; if (i < n) p[i] = 0;
}
__global__ void k_zero_f32(float* __restrict__ p, int n){
  int i = blockIdx.x * 256 + threadIdx.x; if (i < n) p[i] = 0.f;
}

// count incoming edges per dst (incl. self loops)
__global__ void k_count(const int* __restrict__ ei, int E, int N, int* __restrict__ cnt){
  int e = blockIdx.x * 256 + threadIdx.x;
  if (e >= E + N) return;
  int d = (e < E) ? ei[E + e] : (e - E);
  atomicAdd(&cnt[d], 1);
}

// single-block chunked exclusive scan -> row_start[0..N], cur = row_start copy
__global__ __launch_bounds__(1024) void k_scan(const int* __restrict__ cnt, int N,
                                               int* __restrict__ row_start, int* __restrict__ cur){
  __shared__ int sp[1024];
  int t = threadIdx.x;
  int C = (N + 1023) >> 10;
  int lo = t * C, hi = min(lo + C, N);
  int s = 0;
  for (int i = lo; i < hi; ++i) s += cnt[i];
  sp[t] = s;
  __syncthreads();
  for (int off = 1; off < 1024; off <<= 1){
    int v = (t >= off) ? sp[t - off] : 0;
    __syncthreads();
    sp[t] += v;
    __syncthreads();
  }
  int run = (t == 0) ? 0 : sp[t - 1];
  for (int i = lo; i < hi; ++i){ row_start[i] = run; cur[i] = run; run += cnt[i]; }
  if (t == 1023) row_start[N] = sp[1023];
}

__global__ void k_fill(const int* __restrict__ ei, int E, int N,
                       int* __restrict__ cur, int* __restrict__ col){
  int e = blockIdx.x * 256 + threadIdx.x;
  if (e >= E + N) return;
  int s, d;
  if (e < E){ s = ei[e]; d = ei[E + e]; } else { s = e - E; d = s; }
  int pos = atomicAdd(&cur[d], 1);
  col[pos] = s;
}

// ---------------- GEMM: H[N,DOUT](bf16) = X[N,DIN](f32) @ W[DIN,DOUT](f32) ----------------
template<int DIN, int DOUT, int BN>
__global__ __launch_bounds__(256) void k_gemm(const float* __restrict__ X,
                                              const float* __restrict__ W,
                                              ushort* __restrict__ H, int N){
  constexpr int BM = 128, BK = 32, TM = 8;
  constexpr int TN = BN / 16;
  static_assert(DIN % BK == 0 && DOUT % BN == 0 && (TN == 2 || TN == 4), "shape");
  __shared__ float xs[BK][BM];
  __shared__ float wsm[BK][BN];
  int m0 = blockIdx.x * BM;
  int n0 = blockIdx.y * BN;
  int tid = threadIdx.x;
  int tc = tid & 15, tr = tid >> 4;
  float acc[TM][TN];
#pragma unroll
  for (int i = 0; i < TM; ++i)
#pragma unroll
    for (int j = 0; j < TN; ++j) acc[i][j] = 0.f;

  for (int kt = 0; kt < DIN; kt += BK){
    __syncthreads();
    for (int t = tid; t < BM * BK / 4; t += 256){
      int m = t >> 3, kq = t & 7;
      float4 v = make_float4(0.f, 0.f, 0.f, 0.f);
      int row = m0 + m;
      if (row < N) v = *(const float4*)(X + (size_t)row * DIN + kt + kq * 4);
      xs[kq * 4 + 0][m] = v.x; xs[kq * 4 + 1][m] = v.y;
      xs[kq * 4 + 2][m] = v.z; xs[kq * 4 + 3][m] = v.w;
    }
    for (int t = tid; t < BK * BN / 4; t += 256){
      int k = t / (BN / 4), nq = t % (BN / 4);
      float4 v = *(const float4*)(W + (size_t)(kt + k) * DOUT + n0 + nq * 4);
      *(float4*)(&wsm[k][nq * 4]) = v;
    }
    __syncthreads();
#pragma unroll
    for (int k = 0; k < BK; ++k){
      float a[TM], b[TN];
      *(float4*)&a[0] = *(const float4*)&xs[k][tr * TM];
      *(float4*)&a[4] = *(const float4*)&xs[k][tr * TM + 4];
      if constexpr (TN == 4) *(float4*)&b[0] = *(const float4*)&wsm[k][tc * 4];
      else                   *(float2*)&b[0] = *(const float2*)&wsm[k][tc * 2];
#pragma unroll
      for (int i = 0; i < TM; ++i)
#pragma unroll
        for (int j = 0; j < TN; ++j) acc[i][j] = fmaf(a[i], b[j], acc[i][j]);
    }
  }
#pragma unroll
  for (int i = 0; i < TM; ++i){
    int row = m0 + tr * TM + i;
    if (row < N){
      if constexpr (TN == 4){
        uint2 pk;
        pk.x = (uint)f2bf(acc[i][0]) | ((uint)f2bf(acc[i][1]) << 16);
        pk.y = (uint)f2bf(acc[i][2]) | ((uint)f2bf(acc[i][3]) << 16);
        *(uint2*)&H[(size_t)row * DOUT + n0 + tc * 4] = pk;
      } else {
        uint pk = (uint)f2bf(acc[i][0]) | ((uint)f2bf(acc[i][1]) << 16);
        *(uint*)&H[(size_t)row * DOUT + n0 + tc * 2] = pk;
      }
    }
  }
}

// ---------------- attention projections: al_s/al_d = h . a (bf16 H) ----------------
template<int DOUT>
__global__ __launch_bounds__(256) void k_alpha(const ushort* __restrict__ H,
                                               const float* __restrict__ a_src,
                                               const float* __restrict__ a_dst,
                                               float* __restrict__ als, float* __restrict__ ald, int N){
  int wave = threadIdx.x >> 6, lane = threadIdx.x & 63;
  int i = blockIdx.x * 4 + wave;
  if (i >= N) return;
  constexpr int P = DOUT / 2;
  float ss = 0.f, sd = 0.f;
#pragma unroll
  for (int cb = 0; cb < (P + 63) / 64; ++cb){
    int p = cb * 64 + lane;
    if (P % 64 == 0 || p < P){
      uint u = ((const uint*)(H + (size_t)i * DOUT))[p];
      float f0 = __uint_as_float(u << 16);
      float f1 = __uint_as_float(u & 0xffff0000u);
      ss = fmaf(f0, a_src[2 * p], fmaf(f1, a_src[2 * p + 1], ss));
      sd = fmaf(f0, a_dst[2 * p], fmaf(f1, a_dst[2 * p + 1], sd));
    }
  }
  for (int o = 32; o > 0; o >>= 1){ ss += __shfl_xor(ss, o); sd += __shfl_xor(sd, o); }
  if (lane == 0){ als[i] = ss; ald[i] = sd; }
}

// ---------------- fused softmax + weighted gather ----------------
template<int VC>
__device__ __forceinline__ void gacc(float* a, const ushort* __restrict__ H, int DOUTv,
                                     int sn, float w, int cl){
  if constexpr (VC == 4){
    uint2 u = ((const uint2*)(H + (size_t)sn * DOUTv))[cl];
    a[0] = fmaf(w, __uint_as_float(u.x << 16),         a[0]);
    a[1] = fmaf(w, __uint_as_float(u.x & 0xffff0000u), a[1]);
    a[2] = fmaf(w, __uint_as_float(u.y << 16),         a[2]);
    a[3] = fmaf(w, __uint_as_float(u.y & 0xffff0000u), a[3]);
  } else {
    uint u = ((const uint*)(H + (size_t)sn * DOUTv))[cl];
    a[0] = fmaf(w, __uint_as_float(u << 16),           a[0]);
    a[1] = fmaf(w, __uint_as_float(u & 0xffff0000u),   a[1]);
  }
}

template<int DOUT>
__global__ __launch_bounds__(256) void k_agg3(const ushort* __restrict__ H,
                                              const int* __restrict__ rs,
                                              const int* __restrict__ col,
                                              const float* __restrict__ als,
                                              const float* __restrict__ ald,
                                              const float* __restrict__ bias,
                                              float* __restrict__ OUTB, int N){
  constexpr int VC = (DOUT >= 256) ? 4 : 2;            // channels per lane
  constexpr int CL = (DOUT / VC > 64) ? 64 : DOUT / VC; // 16,32,64,64
  constexpr int ES = 64 / CL;                           // edge slots: 4,2,1,1
  int wave = threadIdx.x >> 6, lane = threadIdx.x & 63;
  int i = blockIdx.x * 4 + wave;
  if (i >= N) return;
  int beg = rs[i], end = rs[i + 1], deg = end - beg;
  float ad = ald[i];
  int cl = lane & (CL - 1);

  float s = 0.f;
  float a0[VC], a1[VC], a2[VC], a3[VC];
#pragma unroll
  for (int c = 0; c < VC; ++c){ a0[c] = a1[c] = a2[c] = a3[c] = 0.f; }

  for (int base = 0; base < deg; base += 64){
    int off = base + lane;
    bool valid = off < deg;
    int   sn_v = valid ? col[beg + off] : 0;
    float w_v  = valid ? __expf(leaky(als[sn_v] + ad)) : 0.f;
    s += w_v;
    int cnt = min(64, deg - base);
    if constexpr (ES == 1){
      int k = 0;
      for (; k + 3 < cnt; k += 4){
        int   s0 = __shfl(sn_v, k),     s1 = __shfl(sn_v, k + 1);
        int   s2 = __shfl(sn_v, k + 2), s3 = __shfl(sn_v, k + 3);
        float w0 = __shfl(w_v, k),      w1 = __shfl(w_v, k + 1);
        float w2 = __shfl(w_v, k + 2),  w3 = __shfl(w_v, k + 3);
        gacc<VC>(a0, H, DOUT, s0, w0, cl);
        gacc<VC>(a1, H, DOUT, s1, w1, cl);
        gacc<VC>(a2, H, DOUT, s2, w2, cl);
        gacc<VC>(a3, H, DOUT, s3, w3, cl);
      }
      for (; k < cnt; ++k)
        gacc<VC>(a0, H, DOUT, __shfl(sn_v, k), __shfl(w_v, k), cl);
    } else {
      int es = lane >> (CL == 32 ? 5 : 4); // lane / CL
      int k = 0;
      for (; k + 2 * ES - 1 < cnt; k += 2 * ES){
        int e0 = k + es, e1 = k + ES + es;
        gacc<VC>(a0, H, DOUT, __shfl(sn_v, e0), __shfl(w_v, e0), cl);
        gacc<VC>(a1, H, DOUT, __shfl(sn_v, e1), __shfl(w_v, e1), cl);
      }
      for (; k < cnt; k += ES){
        int e0 = k + es;
        if (e0 < cnt)
          gacc<VC>(a0, H, DOUT, __shfl(sn_v, e0), __shfl(w_v, e0), cl);
      }
    }
  }
  // denominator: reduce across whole wave
  for (int o = 32; o > 0; o >>= 1) s += __shfl_xor(s, o);
  // combine unroll slots
#pragma unroll
  for (int c = 0; c < VC; ++c) a0[c] = (a0[c] + a1[c]) + (a2[c] + a3[c]);
  // reduce across edge-slot groups
  if constexpr (ES > 1){
#pragma unroll
    for (int o = CL; o < 64; o <<= 1)
#pragma unroll
      for (int c = 0; c < VC; ++c) a0[c] += __shfl_xor(a0[c], o);
  }
  if (lane < CL){
    float inv = 1.0f / s;
    int ch = cl * VC;
    float o[VC];
#pragma unroll
    for (int c = 0; c < VC; ++c){
      float x = a0[c] * inv + bias[ch + c];
      o[c] = x > 0.f ? x : __expf(x) - 1.f;
    }
    if constexpr (VC == 4)
      *(float4*)&OUTB[(size_t)i * DOUT + ch] = make_float4(o[0], o[1], o[2], o[3]);
    else
      *(float2*)&OUTB[(size_t)i * DOUT + ch] = make_float2(o[0], o[1]);
  }
}

// ---------------- pooling: per-chunk run-length accumulate ----------------
__global__ __launch_bounds__(256) void k_pool(const float* __restrict__ X4,
                                              const int* __restrict__ batch, int N,
                                              float* __restrict__ g){
  int ch = threadIdx.x; // 256 channels
  int nPer = (N + gridDim.x - 1) / gridDim.x;
  int n0 = blockIdx.x * nPer, n1 = min(n0 + nPer, N);
  if (n0 >= n1) return;
  float acc = 0.f;
  int cg = batch[n0];
  for (int n = n0; n < n1; ++n){
    int gb = batch[n];
    if (gb != cg){ atomicAdd(&g[cg * 256 + ch], acc); acc = 0.f; cg = gb; }
    acc += X4[(size_t)n * 256 + ch];
  }
  atomicAdd(&g[cg * 256 + ch], acc);
}

// ---------------- fused mean + MLP head ----------------
__global__ __launch_bounds__(128) void k_mlp(const float* __restrict__ g,
                                             const int* __restrict__ batch, int N,
                                             const float* __restrict__ l1w, const float* __restrict__ l1b,
                                             const float* __restrict__ l2w, const float* __restrict__ l2b,
                                             float* __restrict__ out){
  __shared__ float gb[256];
  __shared__ float hb[128];
  int gi = blockIdx.x, t = threadIdx.x;
  int lo = lowbound(batch, N, gi);
  int hi = lowbound(batch, N, gi + 1);
  float invc = 1.0f / fmaxf((float)(hi - lo), 1.0f);
  gb[t]       = g[gi * 256 + t] * invc;
  gb[t + 128] = g[gi * 256 + t + 128] * invc;
  __syncthreads();
  float s = l1b[t];
  for (int k = 0; k < 256; ++k) s = fmaf(gb[k], l1w[k * 128 + t], s);
  s = s > 0.f ? s : __expf(s) - 1.f;
  hb[t] = s;
  __syncthreads();
  if (t < 10){
    float o = l2b[t];
    for (int k = 0; k < 128; ++k) o = fmaf(hb[k], l2w[k * 10 + t], o);
    out[gi * 10 + t] = o;
  }
}

// ---------------- host side ----------------
template<int DIN, int DOUT>
static void run_layer(const float* xin, const float* W, const float* asrc, const float* adst,
                      const float* bias, ushort* H, float* OUTB,
                      const int* rs, const int* col, float* als, float* ald,
                      int N, hipStream_t stream){
  constexpr int BN = (DOUT < 64) ? DOUT : 64;
  dim3 grid((N + 127) / 128, DOUT / BN);
  k_gemm<DIN, DOUT, BN><<<grid, 256, 0, stream>>>(xin, W, H, N);
  int nb = (N + 3) / 4;
  k_alpha<DOUT><<<nb, 256, 0, stream>>>(H, asrc, adst, als, ald, N);
  k_agg3<DOUT><<<nb, 256, 0, stream>>>(H, rs, col, als, ald, bias, OUTB, N);
}

extern "C" void kernel_launch(void* const* d_in, const int* in_sizes, int n_in,
                              void* d_out, int out_size, void* d_ws, size_t ws_size,
                              hipStream_t stream){
  const float* x     = (const float*)d_in[0];
  const int*   ei    = (const int*)  d_in[1];
  const int*   batch = (const int*)  d_in[2];
  const float* W1  = (const float*)d_in[3];
  const float* as1 = (const float*)d_in[4];
  const float* ad1 = (const float*)d_in[5];
  const float* b1  = (const float*)d_in[6];
  const float* W2  = (const float*)d_in[7];
  const float* as2 = (const float*)d_in[8];
  const float* ad2 = (const float*)d_in[9];
  const float* b2  = (const float*)d_in[10];
  const float* W3  = (const float*)d_in[11];
  const float* as3 = (const float*)d_in[12];
  const float* ad3 = (const float*)d_in[13];
  const float* b3  = (const float*)d_in[14];
  const float* W4  = (const float*)d_in[15];
  const float* as4 = (const float*)d_in[16];
  const float* ad4 = (const float*)d_in[17];
  const float* b4  = (const float*)d_in[18];
  const float* l1w = (const float*)d_in[19];
  const float* l1b = (const float*)d_in[20];
  const float* l2w = (const float*)d_in[21];
  const float* l2b = (const float*)d_in[22];

  int N  = in_sizes[2];
  int E  = in_sizes[1] / 2;
  int EN = E + N;

  char* p = (char*)d_ws;
  auto alloc = [&](size_t bytes){ void* r = (void*)p; p += (bytes + 255) & ~(size_t)255; return r; };
  ushort* H    = (ushort*)alloc((size_t)N * 256 * 2);
  float*  OUTB = (float*) alloc((size_t)N * 256 * 4);
  int*    cnt  = (int*)   alloc((size_t)N * 4);
  int*    cur  = (int*)   alloc((size_t)N * 4);
  int*    rs   = (int*)   alloc((size_t)(N + 1) * 4);
  int*    col  = (int*)   alloc((size_t)EN * 4);
  float*  als  = (float*) alloc((size_t)N * 4);
  float*  ald  = (float*) alloc((size_t)N * 4);
  float*  g    = (float*) alloc((size_t)NG * 256 * 4);

  // CSR build (by destination, self-loops appended)
  k_zero_i32<<<(N + 255) / 256, 256, 0, stream>>>(cnt, N);
  k_count<<<(EN + 255) / 256, 256, 0, stream>>>(ei, E, N, cnt);
  k_scan<<<1, 1024, 0, stream>>>(cnt, N, rs, cur);
  k_fill<<<(EN + 255) / 256, 256, 0, stream>>>(ei, E, N, cur, col);

  // 4 GAT layers
  run_layer<128,  32>(x,    W1, as1, ad1, b1, H, OUTB, rs, col, als, ald, N, stream);
  run_layer< 32,  64>(OUTB, W2, as2, ad2, b2, H, OUTB, rs, col, als, ald, N, stream);
  run_layer< 64, 128>(OUTB, W3, as3, ad3, b3, H, OUTB, rs, col, als, ald, N, stream);
  run_layer<128, 256>(OUTB, W4, as4, ad4, b4, H, OUTB, rs, col, als, ald, N, stream);

  // global mean pool + MLP head
  k_zero_f32<<<(NG * 256 + 255) / 256, 256, 0, stream>>>(g, NG * 256);
  k_pool<<<1024, 256, 0, stream>>>(OUTB, batch, N, g);
  k_mlp<<<NG, 128, 0, stream>>>(g, batch, N, l1w, l1b, l2w, l2b, (float*)d_out);
}

// Round 4
// 815.678 us; speedup vs baseline: 1.7583x; 1.2580x over previous
//
#include <hip/hip_runtime.h>
#include <math.h>

#define NG 64
#define SC_CHUNK 2048

typedef unsigned int uint;
typedef unsigned short ushort;

__device__ __forceinline__ float leaky(float x){ return x > 0.f ? x : 0.2f*x; }

__device__ __forceinline__ ushort f2bf(float f){
  uint u = __float_as_uint(f);
  uint r = (u + 0x7FFFu + ((u >> 16) & 1u)) >> 16;
  return (ushort)r;
}

__device__ __forceinline__ int lowbound(const int* __restrict__ a, int n, int v){
  int lo = 0, hi = n;
  while (lo < hi){ int mid = (lo + hi) >> 1; if (a[mid] < v) lo = mid + 1; else hi = mid; }
  return lo;
}

__global__ void k_zero_i32(int* __restrict__ p, int n){
  int i = blockIdx.x * 256 + threadIdx.x; if (i < n) p[i] = 0;
}
__global__ void k_zero_f32(float* __restrict__ p, int n){
  int i = blockIdx.x * 256 + threadIdx.x; if (i < n) p[i] = 0.f;
}

// count incoming edges per dst (incl. self loops)
__global__ void k_count(const int* __restrict__ ei, int E, int N, int* __restrict__ cnt){
  int e = blockIdx.x * 256 + threadIdx.x;
  if (e >= E + N) return;
  int d = (e < E) ? ei[E + e] : (e - E);
  atomicAdd(&cnt[d], 1);
}

// ---------------- multi-block exclusive scan of cnt -> row_start/cur ----------------
__global__ __launch_bounds__(256) void k_bsum(const int* __restrict__ cnt, int N,
                                              int* __restrict__ bsum){
  int b = blockIdx.x, t = threadIdx.x;
  int lo = b * SC_CHUNK, hi = min(lo + SC_CHUNK, N);
  int s = 0;
  for (int i = lo + t; i < hi; i += 256) s += cnt[i];
  for (int o = 32; o > 0; o >>= 1) s += __shfl_xor(s, o);
  __shared__ int ws[4];
  if ((t & 63) == 0) ws[t >> 6] = s;
  __syncthreads();
  if (t == 0) bsum[b] = ws[0] + ws[1] + ws[2] + ws[3];
}

// single block scans B (<=1024) block sums; writes exclusive offsets + grand total
__global__ __launch_bounds__(1024) void k_bscan(const int* __restrict__ bsum, int B,
                                                int* __restrict__ boff, int* __restrict__ total){
  __shared__ int sp[1024];
  int t = threadIdx.x;
  int v = (t < B) ? bsum[t] : 0;
  sp[t] = v;
  __syncthreads();
  for (int off = 1; off < 1024; off <<= 1){
    int u = (t >= off) ? sp[t - off] : 0;
    __syncthreads();
    sp[t] += u;
    __syncthreads();
  }
  if (t < B) boff[t] = sp[t] - v;
  if (t == 0) total[0] = (B > 0) ? sp[B - 1] : 0;
}

// per-block local scan (2048 elems, 8/thread) + global offset -> row_start, cur
__global__ __launch_bounds__(256) void k_scatter(const int* __restrict__ cnt, int N,
                                                 const int* __restrict__ boff,
                                                 int* __restrict__ row_start, int* __restrict__ cur){
  int b = blockIdx.x, t = threadIdx.x;
  int base = b * SC_CHUNK + t * 8;
  int v[8]; int s = 0;
#pragma unroll
  for (int k = 0; k < 8; ++k){ int i = base + k; v[k] = (i < N) ? cnt[i] : 0; s += v[k]; }
  __shared__ int sp[256];
  sp[t] = s;
  __syncthreads();
  for (int off = 1; off < 256; off <<= 1){
    int u = (t >= off) ? sp[t - off] : 0;
    __syncthreads();
    sp[t] += u;
    __syncthreads();
  }
  int run = boff[b] + (t ? sp[t - 1] : 0);
#pragma unroll
  for (int k = 0; k < 8; ++k){
    int i = base + k;
    if (i < N){ row_start[i] = run; cur[i] = run; run += v[k]; }
  }
}

__global__ void k_fill(const int* __restrict__ ei, int E, int N,
                       int* __restrict__ cur, int* __restrict__ col){
  int e = blockIdx.x * 256 + threadIdx.x;
  if (e >= E + N) return;
  int s, d;
  if (e < E){ s = ei[e]; d = ei[E + e]; } else { s = e - E; d = s; }
  int pos = atomicAdd(&cur[d], 1);
  col[pos] = s;
}

// ---------------- GEMM: H[N,DOUT](bf16) = X[N,DIN](f32) @ W[DIN,DOUT](f32) ----------------
template<int DIN, int DOUT, int BN>
__global__ __launch_bounds__(256) void k_gemm(const float* __restrict__ X,
                                              const float* __restrict__ W,
                                              ushort* __restrict__ H, int N){
  constexpr int BM = 128, BK = 32, TM = 8;
  constexpr int TN = BN / 16;
  static_assert(DIN % BK == 0 && DOUT % BN == 0 && (TN == 2 || TN == 4), "shape");
  __shared__ float xs[BK][BM];
  __shared__ float wsm[BK][BN];
  int m0 = blockIdx.x * BM;
  int n0 = blockIdx.y * BN;
  int tid = threadIdx.x;
  int tc = tid & 15, tr = tid >> 4;
  float acc[TM][TN];
#pragma unroll
  for (int i = 0; i < TM; ++i)
#pragma unroll
    for (int j = 0; j < TN; ++j) acc[i][j] = 0.f;

  for (int kt = 0; kt < DIN; kt += BK){
    __syncthreads();
    for (int t = tid; t < BM * BK / 4; t += 256){
      int m = t >> 3, kq = t & 7;
      float4 v = make_float4(0.f, 0.f, 0.f, 0.f);
      int row = m0 + m;
      if (row < N) v = *(const float4*)(X + (size_t)row * DIN + kt + kq * 4);
      xs[kq * 4 + 0][m] = v.x; xs[kq * 4 + 1][m] = v.y;
      xs[kq * 4 + 2][m] = v.z; xs[kq * 4 + 3][m] = v.w;
    }
    for (int t = tid; t < BK * BN / 4; t += 256){
      int k = t / (BN / 4), nq = t % (BN / 4);
      float4 v = *(const float4*)(W + (size_t)(kt + k) * DOUT + n0 + nq * 4);
      *(float4*)(&wsm[k][nq * 4]) = v;
    }
    __syncthreads();
#pragma unroll
    for (int k = 0; k < BK; ++k){
      float a[TM], b[TN];
      *(float4*)&a[0] = *(const float4*)&xs[k][tr * TM];
      *(float4*)&a[4] = *(const float4*)&xs[k][tr * TM + 4];
      if constexpr (TN == 4) *(float4*)&b[0] = *(const float4*)&wsm[k][tc * 4];
      else                   *(float2*)&b[0] = *(const float2*)&wsm[k][tc * 2];
#pragma unroll
      for (int i = 0; i < TM; ++i)
#pragma unroll
        for (int j = 0; j < TN; ++j) acc[i][j] = fmaf(a[i], b[j], acc[i][j]);
    }
  }
#pragma unroll
  for (int i = 0; i < TM; ++i){
    int row = m0 + tr * TM + i;
    if (row < N){
      if constexpr (TN == 4){
        uint2 pk;
        pk.x = (uint)f2bf(acc[i][0]) | ((uint)f2bf(acc[i][1]) << 16);
        pk.y = (uint)f2bf(acc[i][2]) | ((uint)f2bf(acc[i][3]) << 16);
        *(uint2*)&H[(size_t)row * DOUT + n0 + tc * 4] = pk;
      } else {
        uint pk = (uint)f2bf(acc[i][0]) | ((uint)f2bf(acc[i][1]) << 16);
        *(uint*)&H[(size_t)row * DOUT + n0 + tc * 2] = pk;
      }
    }
  }
}

// ---------------- attention projections: al_s/al_d = h . a (bf16 H) ----------------
template<int DOUT>
__global__ __launch_bounds__(256) void k_alpha(const ushort* __restrict__ H,
                                               const float* __restrict__ a_src,
                                               const float* __restrict__ a_dst,
                                               float* __restrict__ als, float* __restrict__ ald, int N){
  int wave = threadIdx.x >> 6, lane = threadIdx.x & 63;
  int i = blockIdx.x * 4 + wave;
  if (i >= N) return;
  constexpr int P = DOUT / 2;
  float ss = 0.f, sd = 0.f;
#pragma unroll
  for (int cb = 0; cb < (P + 63) / 64; ++cb){
    int p = cb * 64 + lane;
    if (P % 64 == 0 || p < P){
      uint u = ((const uint*)(H + (size_t)i * DOUT))[p];
      float f0 = __uint_as_float(u << 16);
      float f1 = __uint_as_float(u & 0xffff0000u);
      ss = fmaf(f0, a_src[2 * p], fmaf(f1, a_src[2 * p + 1], ss));
      sd = fmaf(f0, a_dst[2 * p], fmaf(f1, a_dst[2 * p + 1], sd));
    }
  }
  for (int o = 32; o > 0; o >>= 1){ ss += __shfl_xor(ss, o); sd += __shfl_xor(sd, o); }
  if (lane == 0){ als[i] = ss; ald[i] = sd; }
}

// ---------------- fused softmax + weighted gather ----------------
template<int VC>
__device__ __forceinline__ void gacc(float* a, const ushort* __restrict__ H, int DOUTv,
                                     int sn, float w, int cl){
  if constexpr (VC == 4){
    uint2 u = ((const uint2*)(H + (size_t)sn * DOUTv))[cl];
    a[0] = fmaf(w, __uint_as_float(u.x << 16),         a[0]);
    a[1] = fmaf(w, __uint_as_float(u.x & 0xffff0000u), a[1]);
    a[2] = fmaf(w, __uint_as_float(u.y << 16),         a[2]);
    a[3] = fmaf(w, __uint_as_float(u.y & 0xffff0000u), a[3]);
  } else {
    uint u = ((const uint*)(H + (size_t)sn * DOUTv))[cl];
    a[0] = fmaf(w, __uint_as_float(u << 16),           a[0]);
    a[1] = fmaf(w, __uint_as_float(u & 0xffff0000u),   a[1]);
  }
}

template<int DOUT>
__global__ __launch_bounds__(256) void k_agg3(const ushort* __restrict__ H,
                                              const int* __restrict__ rs,
                                              const int* __restrict__ col,
                                              const float* __restrict__ als,
                                              const float* __restrict__ ald,
                                              const float* __restrict__ bias,
                                              float* __restrict__ OUTB, int N){
  constexpr int VC = (DOUT >= 256) ? 4 : 2;            // channels per lane
  constexpr int CL = (DOUT / VC > 64) ? 64 : DOUT / VC; // 16,32,64,64
  constexpr int ES = 64 / CL;                           // edge slots: 4,2,1,1
  int wave = threadIdx.x >> 6, lane = threadIdx.x & 63;
  int i = blockIdx.x * 4 + wave;
  if (i >= N) return;
  int beg = rs[i], end = rs[i + 1], deg = end - beg;
  float ad = ald[i];
  int cl = lane & (CL - 1);

  float s = 0.f;
  float a0[VC], a1[VC], a2[VC], a3[VC];
#pragma unroll
  for (int c = 0; c < VC; ++c){ a0[c] = a1[c] = a2[c] = a3[c] = 0.f; }

  for (int base = 0; base < deg; base += 64){
    int off = base + lane;
    bool valid = off < deg;
    int   sn_v = valid ? col[beg + off] : 0;
    float w_v  = valid ? __expf(leaky(als[sn_v] + ad)) : 0.f;
    s += w_v;
    int cnt = min(64, deg - base);
    if constexpr (ES == 1){
      int k = 0;
      for (; k + 3 < cnt; k += 4){
        int   s0 = __shfl(sn_v, k),     s1 = __shfl(sn_v, k + 1);
        int   s2 = __shfl(sn_v, k + 2), s3 = __shfl(sn_v, k + 3);
        float w0 = __shfl(w_v, k),      w1 = __shfl(w_v, k + 1);
        float w2 = __shfl(w_v, k + 2),  w3 = __shfl(w_v, k + 3);
        gacc<VC>(a0, H, DOUT, s0, w0, cl);
        gacc<VC>(a1, H, DOUT, s1, w1, cl);
        gacc<VC>(a2, H, DOUT, s2, w2, cl);
        gacc<VC>(a3, H, DOUT, s3, w3, cl);
      }
      for (; k < cnt; ++k)
        gacc<VC>(a0, H, DOUT, __shfl(sn_v, k), __shfl(w_v, k), cl);
    } else {
      int es = lane >> (CL == 32 ? 5 : 4); // lane / CL
      int k = 0;
      for (; k + 2 * ES - 1 < cnt; k += 2 * ES){
        int e0 = k + es, e1 = k + ES + es;
        gacc<VC>(a0, H, DOUT, __shfl(sn_v, e0), __shfl(w_v, e0), cl);
        gacc<VC>(a1, H, DOUT, __shfl(sn_v, e1), __shfl(w_v, e1), cl);
      }
      for (; k < cnt; k += ES){
        int e0 = k + es;
        if (e0 < cnt)
          gacc<VC>(a0, H, DOUT, __shfl(sn_v, e0), __shfl(w_v, e0), cl);
      }
    }
  }
  // denominator: reduce across whole wave
  for (int o = 32; o > 0; o >>= 1) s += __shfl_xor(s, o);
  // combine unroll slots
#pragma unroll
  for (int c = 0; c < VC; ++c) a0[c] = (a0[c] + a1[c]) + (a2[c] + a3[c]);
  // reduce across edge-slot groups
  if constexpr (ES > 1){
#pragma unroll
    for (int o = CL; o < 64; o <<= 1)
#pragma unroll
      for (int c = 0; c < VC; ++c) a0[c] += __shfl_xor(a0[c], o);
  }
  if (lane < CL){
    float inv = 1.0f / s;
    int ch = cl * VC;
    float o[VC];
#pragma unroll
    for (int c = 0; c < VC; ++c){
      float x = a0[c] * inv + bias[ch + c];
      o[c] = x > 0.f ? x : __expf(x) - 1.f;
    }
    if constexpr (VC == 4)
      *(float4*)&OUTB[(size_t)i * DOUT + ch] = make_float4(o[0], o[1], o[2], o[3]);
    else
      *(float2*)&OUTB[(size_t)i * DOUT + ch] = make_float2(o[0], o[1]);
  }
}

// ---------------- pooling: per-chunk run-length accumulate ----------------
__global__ __launch_bounds__(256) void k_pool(const float* __restrict__ X4,
                                              const int* __restrict__ batch, int N,
                                              float* __restrict__ g){
  int ch = threadIdx.x; // 256 channels
  int nPer = (N + gridDim.x - 1) / gridDim.x;
  int n0 = blockIdx.x * nPer, n1 = min(n0 + nPer, N);
  if (n0 >= n1) return;
  float acc = 0.f;
  int cg = batch[n0];
  for (int n = n0; n < n1; ++n){
    int gb = batch[n];
    if (gb != cg){ atomicAdd(&g[cg * 256 + ch], acc); acc = 0.f; cg = gb; }
    acc += X4[(size_t)n * 256 + ch];
  }
  atomicAdd(&g[cg * 256 + ch], acc);
}

// ---------------- fused mean + MLP head ----------------
__global__ __launch_bounds__(128) void k_mlp(const float* __restrict__ g,
                                             const int* __restrict__ batch, int N,
                                             const float* __restrict__ l1w, const float* __restrict__ l1b,
                                             const float* __restrict__ l2w, const float* __restrict__ l2b,
                                             float* __restrict__ out){
  __shared__ float gb[256];
  __shared__ float hb[128];
  int gi = blockIdx.x, t = threadIdx.x;
  int lo = lowbound(batch, N, gi);
  int hi = lowbound(batch, N, gi + 1);
  float invc = 1.0f / fmaxf((float)(hi - lo), 1.0f);
  gb[t]       = g[gi * 256 + t] * invc;
  gb[t + 128] = g[gi * 256 + t + 128] * invc;
  __syncthreads();
  float s = l1b[t];
  for (int k = 0; k < 256; ++k) s = fmaf(gb[k], l1w[k * 128 + t], s);
  s = s > 0.f ? s : __expf(s) - 1.f;
  hb[t] = s;
  __syncthreads();
  if (t < 10){
    float o = l2b[t];
    for (int k = 0; k < 128; ++k) o = fmaf(hb[k], l2w[k * 10 + t], o);
    out[gi * 10 + t] = o;
  }
}

// ---------------- host side ----------------
template<int DIN, int DOUT>
static void run_layer(const float* xin, const float* W, const float* asrc, const float* adst,
                      const float* bias, ushort* H, float* OUTB,
                      const int* rs, const int* col, float* als, float* ald,
                      int N, hipStream_t stream){
  constexpr int BN = (DOUT < 64) ? DOUT : 64;
  dim3 grid((N + 127) / 128, DOUT / BN);
  k_gemm<DIN, DOUT, BN><<<grid, 256, 0, stream>>>(xin, W, H, N);
  int nb = (N + 3) / 4;
  k_alpha<DOUT><<<nb, 256, 0, stream>>>(H, asrc, adst, als, ald, N);
  k_agg3<DOUT><<<nb, 256, 0, stream>>>(H, rs, col, als, ald, bias, OUTB, N);
}

extern "C" void kernel_launch(void* const* d_in, const int* in_sizes, int n_in,
                              void* d_out, int out_size, void* d_ws, size_t ws_size,
                              hipStream_t stream){
  const float* x     = (const float*)d_in[0];
  const int*   ei    = (const int*)  d_in[1];
  const int*   batch = (const int*)  d_in[2];
  const float* W1  = (const float*)d_in[3];
  const float* as1 = (const float*)d_in[4];
  const float* ad1 = (const float*)d_in[5];
  const float* b1  = (const float*)d_in[6];
  const float* W2  = (const float*)d_in[7];
  const float* as2 = (const float*)d_in[8];
  const float* ad2 = (const float*)d_in[9];
  const float* b2  = (const float*)d_in[10];
  const float* W3  = (const float*)d_in[11];
  const float* as3 = (const float*)d_in[12];
  const float* ad3 = (const float*)d_in[13];
  const float* b3  = (const float*)d_in[14];
  const float* W4  = (const float*)d_in[15];
  const float* as4 = (const float*)d_in[16];
  const float* ad4 = (const float*)d_in[17];
  const float* b4  = (const float*)d_in[18];
  const float* l1w = (const float*)d_in[19];
  const float* l1b = (const float*)d_in[20];
  const float* l2w = (const float*)d_in[21];
  const float* l2b = (const float*)d_in[22];

  int N  = in_sizes[2];
  int E  = in_sizes[1] / 2;
  int EN = E + N;
  int B  = (N + SC_CHUNK - 1) / SC_CHUNK;

  char* p = (char*)d_ws;
  auto alloc = [&](size_t bytes){ void* r = (void*)p; p += (bytes + 255) & ~(size_t)255; return r; };
  ushort* H    = (ushort*)alloc((size_t)N * 256 * 2);
  float*  OUTB = (float*) alloc((size_t)N * 256 * 4);
  int*    cnt  = (int*)   alloc((size_t)N * 4);
  int*    cur  = (int*)   alloc((size_t)N * 4);
  int*    rs   = (int*)   alloc((size_t)(N + 1) * 4);
  int*    col  = (int*)   alloc((size_t)EN * 4);
  float*  als  = (float*) alloc((size_t)N * 4);
  float*  ald  = (float*) alloc((size_t)N * 4);
  float*  g    = (float*) alloc((size_t)NG * 256 * 4);
  int*    bsum = (int*)   alloc((size_t)1024 * 4);
  int*    boff = (int*)   alloc((size_t)1024 * 4);

  // CSR build (by destination, self-loops appended)
  k_zero_i32<<<(N + 255) / 256, 256, 0, stream>>>(cnt, N);
  k_count<<<(EN + 255) / 256, 256, 0, stream>>>(ei, E, N, cnt);
  k_bsum<<<B, 256, 0, stream>>>(cnt, N, bsum);
  k_bscan<<<1, 1024, 0, stream>>>(bsum, B, boff, rs + N); // rs[N] = total = EN
  k_scatter<<<B, 256, 0, stream>>>(cnt, N, boff, rs, cur);
  k_fill<<<(EN + 255) / 256, 256, 0, stream>>>(ei, E, N, cur, col);

  // 4 GAT layers
  run_layer<128,  32>(x,    W1, as1, ad1, b1, H, OUTB, rs, col, als, ald, N, stream);
  run_layer< 32,  64>(OUTB, W2, as2, ad2, b2, H, OUTB, rs, col, als, ald, N, stream);
  run_layer< 64, 128>(OUTB, W3, as3, ad3, b3, H, OUTB, rs, col, als, ald, N, stream);
  run_layer<128, 256>(OUTB, W4, as4, ad4, b4, H, OUTB, rs, col, als, ald, N, stream);

  // global mean pool + MLP head
  k_zero_f32<<<(NG * 256 + 255) / 256, 256, 0, stream>>>(g, NG * 256);
  k_pool<<<1024, 256, 0, stream>>>(OUTB, batch, N, g);
  k_mlp<<<NG, 128, 0, stream>>>(g, batch, N, l1w, l1b, l2w, l2b, (float*)d_out);
}

// Round 5
// 782.910 us; speedup vs baseline: 1.8319x; 1.0419x over previous
//
#include <hip/hip_runtime.h>
#include <math.h>

#define NG 64
#define SC_CHUNK 2048
#define FILL_P 4

typedef unsigned int uint;
typedef unsigned short ushort;

__device__ __forceinline__ float leaky(float x){ return x > 0.f ? x : 0.2f*x; }

__device__ __forceinline__ ushort f2bf(float f){
  uint u = __float_as_uint(f);
  uint r = (u + 0x7FFFu + ((u >> 16) & 1u)) >> 16;
  return (ushort)r;
}

__device__ __forceinline__ int lowbound(const int* __restrict__ a, int n, int v){
  int lo = 0, hi = n;
  while (lo < hi){ int mid = (lo + hi) >> 1; if (a[mid] < v) lo = mid + 1; else hi = mid; }
  return lo;
}

__global__ void k_zero_i32(int* __restrict__ p, int n){
  int i = blockIdx.x * 256 + threadIdx.x; if (i < n) p[i] = 0;
}
__global__ void k_zero_f32(float* __restrict__ p, int n){
  int i = blockIdx.x * 256 + threadIdx.x; if (i < n) p[i] = 0.f;
}

// count incoming edges per dst (incl. self loops)
__global__ void k_count(const int* __restrict__ ei, int E, int N, int* __restrict__ cnt){
  int e = blockIdx.x * 256 + threadIdx.x;
  if (e >= E + N) return;
  int d = (e < E) ? __builtin_nontemporal_load(ei + E + e) : (e - E);
  atomicAdd(&cnt[d], 1);
}

// ---------------- multi-block exclusive scan of cnt -> row_start/cur ----------------
__global__ __launch_bounds__(256) void k_bsum(const int* __restrict__ cnt, int N,
                                              int* __restrict__ bsum){
  int b = blockIdx.x, t = threadIdx.x;
  int lo = b * SC_CHUNK, hi = min(lo + SC_CHUNK, N);
  int s = 0;
  for (int i = lo + t; i < hi; i += 256) s += cnt[i];
  for (int o = 32; o > 0; o >>= 1) s += __shfl_xor(s, o);
  __shared__ int ws[4];
  if ((t & 63) == 0) ws[t >> 6] = s;
  __syncthreads();
  if (t == 0) bsum[b] = ws[0] + ws[1] + ws[2] + ws[3];
}

// single block scans B (<=1024) block sums; writes exclusive offsets + grand total
__global__ __launch_bounds__(1024) void k_bscan(const int* __restrict__ bsum, int B,
                                                int* __restrict__ boff, int* __restrict__ total){
  __shared__ int sp[1024];
  int t = threadIdx.x;
  int v = (t < B) ? bsum[t] : 0;
  sp[t] = v;
  __syncthreads();
  for (int off = 1; off < 1024; off <<= 1){
    int u = (t >= off) ? sp[t - off] : 0;
    __syncthreads();
    sp[t] += u;
    __syncthreads();
  }
  if (t < B) boff[t] = sp[t] - v;
  if (t == 0) total[0] = (B > 0) ? sp[B - 1] : 0;
}

// per-block local scan (2048 elems, 8/thread) + global offset -> row_start, cur
__global__ __launch_bounds__(256) void k_scatter(const int* __restrict__ cnt, int N,
                                                 const int* __restrict__ boff,
                                                 int* __restrict__ row_start, int* __restrict__ cur){
  int b = blockIdx.x, t = threadIdx.x;
  int base = b * SC_CHUNK + t * 8;
  int v[8]; int s = 0;
#pragma unroll
  for (int k = 0; k < 8; ++k){ int i = base + k; v[k] = (i < N) ? cnt[i] : 0; s += v[k]; }
  __shared__ int sp[256];
  sp[t] = s;
  __syncthreads();
  for (int off = 1; off < 256; off <<= 1){
    int u = (t >= off) ? sp[t - off] : 0;
    __syncthreads();
    sp[t] += u;
    __syncthreads();
  }
  int run = boff[b] + (t ? sp[t - 1] : 0);
#pragma unroll
  for (int k = 0; k < 8; ++k){
    int i = base + k;
    if (i < N){ row_start[i] = run; cur[i] = run; run += v[k]; }
  }
}

// dst-range pass: scatter only edges with dst in [dlo,dhi) -> contiguous col window
__global__ void k_fill(const int* __restrict__ ei, int E, int N, int dlo, int dhi,
                       int* __restrict__ cur, int* __restrict__ col){
  int e = blockIdx.x * 256 + threadIdx.x;
  if (e >= E + N) return;
  int s, d;
  if (e < E){
    d = __builtin_nontemporal_load(ei + E + e);
    s = __builtin_nontemporal_load(ei + e);
  } else { s = e - E; d = s; }
  if (d < dlo || d >= dhi) return;
  int pos = atomicAdd(&cur[d], 1);
  col[pos] = s;
}

// ---------------- GEMM: H[N,DOUT](bf16) = X[N,DIN](f32) @ W[DIN,DOUT](f32) ----------------
template<int DIN, int DOUT, int BN>
__global__ __launch_bounds__(256) void k_gemm(const float* __restrict__ X,
                                              const float* __restrict__ W,
                                              ushort* __restrict__ H, int N){
  constexpr int BM = 128, BK = 32, TM = 8;
  constexpr int TN = BN / 16;
  static_assert(DIN % BK == 0 && DOUT % BN == 0 && (TN == 2 || TN == 4), "shape");
  __shared__ float xs[BK][BM];
  __shared__ float wsm[BK][BN];
  int m0 = blockIdx.x * BM;
  int n0 = blockIdx.y * BN;
  int tid = threadIdx.x;
  int tc = tid & 15, tr = tid >> 4;
  float acc[TM][TN];
#pragma unroll
  for (int i = 0; i < TM; ++i)
#pragma unroll
    for (int j = 0; j < TN; ++j) acc[i][j] = 0.f;

  for (int kt = 0; kt < DIN; kt += BK){
    __syncthreads();
    for (int t = tid; t < BM * BK / 4; t += 256){
      int m = t >> 3, kq = t & 7;
      float4 v = make_float4(0.f, 0.f, 0.f, 0.f);
      int row = m0 + m;
      if (row < N) v = *(const float4*)(X + (size_t)row * DIN + kt + kq * 4);
      xs[kq * 4 + 0][m] = v.x; xs[kq * 4 + 1][m] = v.y;
      xs[kq * 4 + 2][m] = v.z; xs[kq * 4 + 3][m] = v.w;
    }
    for (int t = tid; t < BK * BN / 4; t += 256){
      int k = t / (BN / 4), nq = t % (BN / 4);
      float4 v = *(const float4*)(W + (size_t)(kt + k) * DOUT + n0 + nq * 4);
      *(float4*)(&wsm[k][nq * 4]) = v;
    }
    __syncthreads();
#pragma unroll
    for (int k = 0; k < BK; ++k){
      float a[TM], b[TN];
      *(float4*)&a[0] = *(const float4*)&xs[k][tr * TM];
      *(float4*)&a[4] = *(const float4*)&xs[k][tr * TM + 4];
      if constexpr (TN == 4) *(float4*)&b[0] = *(const float4*)&wsm[k][tc * 4];
      else                   *(float2*)&b[0] = *(const float2*)&wsm[k][tc * 2];
#pragma unroll
      for (int i = 0; i < TM; ++i)
#pragma unroll
        for (int j = 0; j < TN; ++j) acc[i][j] = fmaf(a[i], b[j], acc[i][j]);
    }
  }
#pragma unroll
  for (int i = 0; i < TM; ++i){
    int row = m0 + tr * TM + i;
    if (row < N){
      if constexpr (TN == 4){
        uint2 pk;
        pk.x = (uint)f2bf(acc[i][0]) | ((uint)f2bf(acc[i][1]) << 16);
        pk.y = (uint)f2bf(acc[i][2]) | ((uint)f2bf(acc[i][3]) << 16);
        *(uint2*)&H[(size_t)row * DOUT + n0 + tc * 4] = pk;
      } else {
        uint pk = (uint)f2bf(acc[i][0]) | ((uint)f2bf(acc[i][1]) << 16);
        *(uint*)&H[(size_t)row * DOUT + n0 + tc * 2] = pk;
      }
    }
  }
}

// ---------------- attention projections: al_s/al_d = h . a (bf16 H) ----------------
template<int DOUT>
__global__ __launch_bounds__(256) void k_alpha(const ushort* __restrict__ H,
                                               const float* __restrict__ a_src,
                                               const float* __restrict__ a_dst,
                                               float* __restrict__ als, float* __restrict__ ald, int N){
  int wave = threadIdx.x >> 6, lane = threadIdx.x & 63;
  int i = blockIdx.x * 4 + wave;
  if (i >= N) return;
  constexpr int P = DOUT / 2;
  float ss = 0.f, sd = 0.f;
#pragma unroll
  for (int cb = 0; cb < (P + 63) / 64; ++cb){
    int p = cb * 64 + lane;
    if (P % 64 == 0 || p < P){
      uint u = ((const uint*)(H + (size_t)i * DOUT))[p];
      float f0 = __uint_as_float(u << 16);
      float f1 = __uint_as_float(u & 0xffff0000u);
      ss = fmaf(f0, a_src[2 * p], fmaf(f1, a_src[2 * p + 1], ss));
      sd = fmaf(f0, a_dst[2 * p], fmaf(f1, a_dst[2 * p + 1], sd));
    }
  }
  for (int o = 32; o > 0; o >>= 1){ ss += __shfl_xor(ss, o); sd += __shfl_xor(sd, o); }
  if (lane == 0){ als[i] = ss; ald[i] = sd; }
}

// ---------------- fused softmax + weighted gather ----------------
template<int VC>
__device__ __forceinline__ void gacc(float* a, const ushort* __restrict__ H, int DOUTv,
                                     int sn, float w, int cl){
  if constexpr (VC == 4){
    uint2 u = ((const uint2*)(H + (size_t)sn * DOUTv))[cl];
    a[0] = fmaf(w, __uint_as_float(u.x << 16),         a[0]);
    a[1] = fmaf(w, __uint_as_float(u.x & 0xffff0000u), a[1]);
    a[2] = fmaf(w, __uint_as_float(u.y << 16),         a[2]);
    a[3] = fmaf(w, __uint_as_float(u.y & 0xffff0000u), a[3]);
  } else {
    uint u = ((const uint*)(H + (size_t)sn * DOUTv))[cl];
    a[0] = fmaf(w, __uint_as_float(u << 16),           a[0]);
    a[1] = fmaf(w, __uint_as_float(u & 0xffff0000u),   a[1]);
  }
}

template<int DOUT>
__global__ __launch_bounds__(256) void k_agg3(const ushort* __restrict__ H,
                                              const int* __restrict__ rs,
                                              const int* __restrict__ col,
                                              const float* __restrict__ als,
                                              const float* __restrict__ ald,
                                              const float* __restrict__ bias,
                                              float* __restrict__ OUTB, int N){
  constexpr int VC = (DOUT >= 256) ? 4 : 2;            // channels per lane
  constexpr int CL = (DOUT / VC > 64) ? 64 : DOUT / VC; // 16,32,64,64
  constexpr int ES = 64 / CL;                           // edge slots: 4,2,1,1
  int wave = threadIdx.x >> 6, lane = threadIdx.x & 63;
  int i = blockIdx.x * 4 + wave;
  if (i >= N) return;
  int beg = rs[i], end = rs[i + 1], deg = end - beg;
  float ad = ald[i];
  int cl = lane & (CL - 1);

  float s = 0.f;
  float a0[VC], a1[VC], a2[VC], a3[VC];
#pragma unroll
  for (int c = 0; c < VC; ++c){ a0[c] = a1[c] = a2[c] = a3[c] = 0.f; }

  for (int base = 0; base < deg; base += 64){
    int off = base + lane;
    bool valid = off < deg;
    int   sn_v = valid ? col[beg + off] : 0;
    float w_v  = valid ? __expf(leaky(als[sn_v] + ad)) : 0.f;
    s += w_v;
    int cnt = min(64, deg - base);
    if constexpr (ES == 1){
      int k = 0;
      for (; k + 3 < cnt; k += 4){
        int   s0 = __shfl(sn_v, k),     s1 = __shfl(sn_v, k + 1);
        int   s2 = __shfl(sn_v, k + 2), s3 = __shfl(sn_v, k + 3);
        float w0 = __shfl(w_v, k),      w1 = __shfl(w_v, k + 1);
        float w2 = __shfl(w_v, k + 2),  w3 = __shfl(w_v, k + 3);
        gacc<VC>(a0, H, DOUT, s0, w0, cl);
        gacc<VC>(a1, H, DOUT, s1, w1, cl);
        gacc<VC>(a2, H, DOUT, s2, w2, cl);
        gacc<VC>(a3, H, DOUT, s3, w3, cl);
      }
      for (; k < cnt; ++k)
        gacc<VC>(a0, H, DOUT, __shfl(sn_v, k), __shfl(w_v, k), cl);
    } else {
      int es = lane >> (CL == 32 ? 5 : 4); // lane / CL
      int k = 0;
      for (; k + 2 * ES - 1 < cnt; k += 2 * ES){
        int e0 = k + es, e1 = k + ES + es;
        gacc<VC>(a0, H, DOUT, __shfl(sn_v, e0), __shfl(w_v, e0), cl);
        gacc<VC>(a1, H, DOUT, __shfl(sn_v, e1), __shfl(w_v, e1), cl);
      }
      for (; k < cnt; k += ES){
        int e0 = k + es;
        if (e0 < cnt)
          gacc<VC>(a0, H, DOUT, __shfl(sn_v, e0), __shfl(w_v, e0), cl);
      }
    }
  }
  // denominator: reduce across whole wave
  for (int o = 32; o > 0; o >>= 1) s += __shfl_xor(s, o);
  // combine unroll slots
#pragma unroll
  for (int c = 0; c < VC; ++c) a0[c] = (a0[c] + a1[c]) + (a2[c] + a3[c]);
  // reduce across edge-slot groups
  if constexpr (ES > 1){
#pragma unroll
    for (int o = CL; o < 64; o <<= 1)
#pragma unroll
      for (int c = 0; c < VC; ++c) a0[c] += __shfl_xor(a0[c], o);
  }
  if (lane < CL){
    float inv = 1.0f / s;
    int ch = cl * VC;
    float o[VC];
#pragma unroll
    for (int c = 0; c < VC; ++c){
      float x = a0[c] * inv + bias[ch + c];
      o[c] = x > 0.f ? x : __expf(x) - 1.f;
    }
    if constexpr (VC == 4)
      *(float4*)&OUTB[(size_t)i * DOUT + ch] = make_float4(o[0], o[1], o[2], o[3]);
    else
      *(float2*)&OUTB[(size_t)i * DOUT + ch] = make_float2(o[0], o[1]);
  }
}

// ---------------- pooling: per-chunk run-length accumulate ----------------
__global__ __launch_bounds__(256) void k_pool(const float* __restrict__ X4,
                                              const int* __restrict__ batch, int N,
                                              float* __restrict__ g){
  int ch = threadIdx.x; // 256 channels
  int nPer = (N + gridDim.x - 1) / gridDim.x;
  int n0 = blockIdx.x * nPer, n1 = min(n0 + nPer, N);
  if (n0 >= n1) return;
  float acc = 0.f;
  int cg = batch[n0];
  for (int n = n0; n < n1; ++n){
    int gb = batch[n];
    if (gb != cg){ atomicAdd(&g[cg * 256 + ch], acc); acc = 0.f; cg = gb; }
    acc += X4[(size_t)n * 256 + ch];
  }
  atomicAdd(&g[cg * 256 + ch], acc);
}

// ---------------- fused mean + MLP head ----------------
__global__ __launch_bounds__(128) void k_mlp(const float* __restrict__ g,
                                             const int* __restrict__ batch, int N,
                                             const float* __restrict__ l1w, const float* __restrict__ l1b,
                                             const float* __restrict__ l2w, const float* __restrict__ l2b,
                                             float* __restrict__ out){
  __shared__ float gb[256];
  __shared__ float hb[128];
  int gi = blockIdx.x, t = threadIdx.x;
  int lo = lowbound(batch, N, gi);
  int hi = lowbound(batch, N, gi + 1);
  float invc = 1.0f / fmaxf((float)(hi - lo), 1.0f);
  gb[t]       = g[gi * 256 + t] * invc;
  gb[t + 128] = g[gi * 256 + t + 128] * invc;
  __syncthreads();
  float s = l1b[t];
  for (int k = 0; k < 256; ++k) s = fmaf(gb[k], l1w[k * 128 + t], s);
  s = s > 0.f ? s : __expf(s) - 1.f;
  hb[t] = s;
  __syncthreads();
  if (t < 10){
    float o = l2b[t];
    for (int k = 0; k < 128; ++k) o = fmaf(hb[k], l2w[k * 10 + t], o);
    out[gi * 10 + t] = o;
  }
}

// ---------------- host side ----------------
template<int DIN, int DOUT>
static void run_layer(const float* xin, const float* W, const float* asrc, const float* adst,
                      const float* bias, ushort* H, float* OUTB,
                      const int* rs, const int* col, float* als, float* ald,
                      int N, hipStream_t stream){
  constexpr int BN = (DOUT < 64) ? DOUT : 64;
  dim3 grid((N + 127) / 128, DOUT / BN);
  k_gemm<DIN, DOUT, BN><<<grid, 256, 0, stream>>>(xin, W, H, N);
  int nb = (N + 3) / 4;
  k_alpha<DOUT><<<nb, 256, 0, stream>>>(H, asrc, adst, als, ald, N);
  k_agg3<DOUT><<<nb, 256, 0, stream>>>(H, rs, col, als, ald, bias, OUTB, N);
}

extern "C" void kernel_launch(void* const* d_in, const int* in_sizes, int n_in,
                              void* d_out, int out_size, void* d_ws, size_t ws_size,
                              hipStream_t stream){
  const float* x     = (const float*)d_in[0];
  const int*   ei    = (const int*)  d_in[1];
  const int*   batch = (const int*)  d_in[2];
  const float* W1  = (const float*)d_in[3];
  const float* as1 = (const float*)d_in[4];
  const float* ad1 = (const float*)d_in[5];
  const float* b1  = (const float*)d_in[6];
  const float* W2  = (const float*)d_in[7];
  const float* as2 = (const float*)d_in[8];
  const float* ad2 = (const float*)d_in[9];
  const float* b2  = (const float*)d_in[10];
  const float* W3  = (const float*)d_in[11];
  const float* as3 = (const float*)d_in[12];
  const float* ad3 = (const float*)d_in[13];
  const float* b3  = (const float*)d_in[14];
  const float* W4  = (const float*)d_in[15];
  const float* as4 = (const float*)d_in[16];
  const float* ad4 = (const float*)d_in[17];
  const float* b4  = (const float*)d_in[18];
  const float* l1w = (const float*)d_in[19];
  const float* l1b = (const float*)d_in[20];
  const float* l2w = (const float*)d_in[21];
  const float* l2b = (const float*)d_in[22];

  int N  = in_sizes[2];
  int E  = in_sizes[1] / 2;
  int EN = E + N;
  int B  = (N + SC_CHUNK - 1) / SC_CHUNK;

  char* p = (char*)d_ws;
  auto alloc = [&](size_t bytes){ void* r = (void*)p; p += (bytes + 255) & ~(size_t)255; return r; };
  ushort* H    = (ushort*)alloc((size_t)N * 256 * 2);
  float*  OUTB = (float*) alloc((size_t)N * 256 * 4);
  int*    cnt  = (int*)   alloc((size_t)N * 4);
  int*    cur  = (int*)   alloc((size_t)N * 4);
  int*    rs   = (int*)   alloc((size_t)(N + 1) * 4);
  int*    col  = (int*)   alloc((size_t)EN * 4);
  float*  als  = (float*) alloc((size_t)N * 4);
  float*  ald  = (float*) alloc((size_t)N * 4);
  float*  g    = (float*) alloc((size_t)NG * 256 * 4);
  int*    bsum = (int*)   alloc((size_t)1024 * 4);
  int*    boff = (int*)   alloc((size_t)1024 * 4);

  // CSR build (by destination, self-loops appended)
  k_zero_i32<<<(N + 255) / 256, 256, 0, stream>>>(cnt, N);
  k_count<<<(EN + 255) / 256, 256, 0, stream>>>(ei, E, N, cnt);
  k_bsum<<<B, 256, 0, stream>>>(cnt, N, bsum);
  k_bscan<<<1, 1024, 0, stream>>>(bsum, B, boff, rs + N); // rs[N] = total = EN
  k_scatter<<<B, 256, 0, stream>>>(cnt, N, boff, rs, cur);
  // dst-range passes: small contiguous col window per pass -> L2-merged writes
  {
    int W = (N + FILL_P - 1) / FILL_P;
    for (int pss = 0; pss < FILL_P; ++pss){
      int dlo = pss * W, dhi = min(dlo + W, N);
      if (dlo < dhi)
        k_fill<<<(EN + 255) / 256, 256, 0, stream>>>(ei, E, N, dlo, dhi, cur, col);
    }
  }

  // 4 GAT layers
  run_layer<128,  32>(x,    W1, as1, ad1, b1, H, OUTB, rs, col, als, ald, N, stream);
  run_layer< 32,  64>(OUTB, W2, as2, ad2, b2, H, OUTB, rs, col, als, ald, N, stream);
  run_layer< 64, 128>(OUTB, W3, as3, ad3, b3, H, OUTB, rs, col, als, ald, N, stream);
  run_layer<128, 256>(OUTB, W4, as4, ad4, b4, H, OUTB, rs, col, als, ald, N, stream);

  // global mean pool + MLP head
  k_zero_f32<<<(NG * 256 + 255) / 256, 256, 0, stream>>>(g, NG * 256);
  k_pool<<<1024, 256, 0, stream>>>(OUTB, batch, N, g);
  k_mlp<<<NG, 128, 0, stream>>>(g, batch, N, l1w, l1b, l2w, l2b, (float*)d_out);
}